// Round 4
// baseline (1996.178 us; speedup 1.0000x reference)
//
#include <hip/hip_runtime.h>

typedef float f32x4 __attribute__((ext_vector_type(4)));
typedef short bf16x8 __attribute__((ext_vector_type(8)));
typedef unsigned short u16;
typedef unsigned int u32;

#define SCALE 0.0625f
#define MFMA16(a, b, c) __builtin_amdgcn_mfma_f32_16x16x32_bf16((a), (b), (c), 0, 0, 0)

__device__ inline u16 f2bf(float x) {
  u32 u = __float_as_uint(x);
  u32 r = u + 0x7FFFu + ((u >> 16) & 1u);
  return (u16)(r >> 16);
}
__device__ inline float bf2f(u16 h) { return __uint_as_float(((u32)h) << 16); }

// ---------------------------------------------------------------------------
// Transpose+split W matrices: W[k][n] fp32 -> Wt_hi/lo[n][k] bf16.
// ---------------------------------------------------------------------------
__global__ __launch_bounds__(256) void convert_w(
    const float* __restrict__ Wq, const float* __restrict__ Wk, const float* __restrict__ Wv,
    u16* __restrict__ qh, u16* __restrict__ qlo2, u16* __restrict__ kh, u16* __restrict__ klo2,
    u16* __restrict__ vh, u16* __restrict__ vlo2) {
  int idx = blockIdx.x * 256 + threadIdx.x;
  const float* src;
  u16 *dh, *dl;
  int KD;
  const int nq = 416 * 256;
  if (idx < nq) {
    src = Wq; dh = qh; dl = qlo2; KD = 416;
  } else if (idx < 2 * nq) {
    idx -= nq; src = Wk; dh = kh; dl = klo2; KD = 416;
  } else {
    idx -= 2 * nq;
    if (idx >= 384 * 256) return;
    src = Wv; dh = vh; dl = vlo2; KD = 384;
  }
  int k = idx >> 8, n = idx & 255;
  float x = src[idx];
  u16 h = f2bf(x);
  dh[n * KD + k] = h;
  dl[n * KD + k] = f2bf(x - bf2f(h));
}

// ---------------------------------------------------------------------------
// Projection GEMM, split-bf16 MFMA: C[m][256] = A[m][KD] @ W[KD][256].
// ---------------------------------------------------------------------------
template <int KD, bool TRANS_OUT>
__global__ __launch_bounds__(256, 3) void proj_mfma(
    const float* __restrict__ A, const u16* __restrict__ wth, const u16* __restrict__ wtl,
    u16* __restrict__ oh, u16* __restrict__ ol) {
  __shared__ u16 Ah[64 * 32], Al[64 * 32];
  __shared__ u16 Wh[256 * 32], Wl[256 * 32];
  const int t = threadIdx.x;
  const int w = t >> 6, l = t & 63;
  const int lr = l & 15, lk = l >> 4;
  const int m0 = blockIdx.x * 64;
  f32x4 acc[16];
#pragma unroll
  for (int i = 0; i < 16; ++i) acc[i] = {};
  const int arow = t >> 2, ac = t & 3;
  const int acp = (ac + (arow >> 1)) & 3;
  for (int k0 = 0; k0 < KD; k0 += 32) {
    __syncthreads();
    {
      const float* s1 = A + (size_t)(m0 + arow) * KD + k0 + ac * 8;
      float4 f1 = *(const float4*)s1;
      float4 f2 = *(const float4*)(s1 + 4);
      float fs[8] = {f1.x, f1.y, f1.z, f1.w, f2.x, f2.y, f2.z, f2.w};
      bf16x8 hv, lv;
#pragma unroll
      for (int j = 0; j < 8; ++j) {
        u16 h = f2bf(fs[j]);
        hv[j] = (short)h;
        lv[j] = (short)f2bf(fs[j] - bf2f(h));
      }
      *(bf16x8*)(Ah + arow * 32 + acp * 8) = hv;
      *(bf16x8*)(Al + arow * 32 + acp * 8) = lv;
#pragma unroll
      for (int i = 0; i < 4; ++i) {
        int ch = t + i * 256;
        int n = ch >> 2, c = ch & 3;
        int cp = (c + (n >> 1)) & 3;
        *(bf16x8*)(Wh + n * 32 + cp * 8) = *(const bf16x8*)(wth + (size_t)n * KD + k0 + c * 8);
        *(bf16x8*)(Wl + n * 32 + cp * 8) = *(const bf16x8*)(wtl + (size_t)n * KD + k0 + c * 8);
      }
    }
    __syncthreads();
    const int row = w * 16 + lr;
    const int rcp = (lk + (row >> 1)) & 3;
    bf16x8 ah = *(const bf16x8*)(Ah + row * 32 + rcp * 8);
    bf16x8 al = *(const bf16x8*)(Al + row * 32 + rcp * 8);
#pragma unroll
    for (int fc = 0; fc < 16; ++fc) {
      int n = lr + 16 * fc;
      int cp = (lk + (n >> 1)) & 3;
      bf16x8 bh = *(const bf16x8*)(Wh + n * 32 + cp * 8);
      bf16x8 bl = *(const bf16x8*)(Wl + n * 32 + cp * 8);
      acc[fc] = MFMA16(ah, bh, acc[fc]);
      acc[fc] = MFMA16(ah, bl, acc[fc]);
      acc[fc] = MFMA16(al, bh, acc[fc]);
    }
  }
  if (!TRANS_OUT) {
#pragma unroll
    for (int fc = 0; fc < 16; ++fc) {
      int n = lr + 16 * fc;
#pragma unroll
      for (int r = 0; r < 4; ++r) {
        int m = m0 + w * 16 + lk * 4 + r;
        float v = acc[fc][r];
        u16 h = f2bf(v);
        oh[(size_t)m * 256 + n] = h;
        ol[(size_t)m * 256 + n] = f2bf(v - bf2f(h));
      }
    }
  } else {
    const int km = m0 / 576;
    const int j0 = (m0 % 576) + w * 16 + lk * 4;
#pragma unroll
    for (int fc = 0; fc < 16; ++fc) {
      int n = lr + 16 * fc;
      u16 hs[4], ls[4];
#pragma unroll
      for (int r = 0; r < 4; ++r) {
        float v = acc[fc][r];
        u16 h = f2bf(v);
        hs[r] = h;
        ls[r] = f2bf(v - bf2f(h));
      }
      size_t base = ((size_t)km * 256 + n) * 576 + j0;
      *(ushort4*)(oh + base) = make_ushort4(hs[0], hs[1], hs[2], hs[3]);
      *(ushort4*)(ol + base) = make_ushort4(ls[0], ls[1], ls[2], ls[3]);
    }
  }
}

// ---------------------------------------------------------------------------
// Flash attention per (b, km, qtile64), m==0 softmax.
// LDS holds only HI tiles (K 16KB + V 16KB) + shared P (10KB) -> 3 blocks/CU.
// LO operand fragments are loaded per-wave directly from global (L2-resident
// via XCD km-cluster swizzle).  PV is d-split across the 4 waves (P shared
// through LDS), cutting per-wave LDS reads 66 -> 28 b128 per kt.
// ---------------------------------------------------------------------------
__global__ __launch_bounds__(256, 3) void attn_kernel(
    const u16* __restrict__ qhi, const u16* __restrict__ qlo,
    const u16* __restrict__ khi, const u16* __restrict__ klo,
    const u16* __restrict__ vthi, const u16* __restrict__ vtlo,
    float* __restrict__ rpartT, float* __restrict__ invl) {
  __shared__ u16 Kh[32 * 256];   // [key j][256 d], chunk swz c^(j&7)
  __shared__ u16 Vh[256 * 32];   // [d][32 j], chunk swz (c+(d>>1))&3
  __shared__ u16 Ph[64 * 40];    // P hi, [64 q][32 j] stride 40
  __shared__ u16 Pl[64 * 40];    // P lo
  __shared__ float invs[64];
  const int t = threadIdx.x;
  const int w = t >> 6, l = t & 63;
  const int lr = l & 15, lk = l >> 4;
  // XCD-cluster swizzle: all 36 blocks of one km land on xcd = km%8.
  const int L = blockIdx.x;
  const int xcd = L & 7, slot = L >> 3;
  const int km = xcd + 8 * (slot / 36);
  const int inner = slot % 36;
  const int b = inner & 3, qb = inner >> 2;
  const int qw = qb * 64 + w * 16;

  bf16x8 qh[8], ql[8];
  {
    const u16* ph = qhi + ((size_t)(b * 576 + qw + lr)) * 256 + lk * 8;
    const u16* pl = qlo + ((size_t)(b * 576 + qw + lr)) * 256 + lk * 8;
#pragma unroll
    for (int s = 0; s < 8; ++s) {
      qh[s] = *(const bf16x8*)(ph + s * 32);
      ql[s] = *(const bf16x8*)(pl + s * 32);
    }
  }

  f32x4 o[4][4];
#pragma unroll
  for (int i = 0; i < 4; ++i)
#pragma unroll
    for (int j = 0; j < 4; ++j) o[i][j] = {};
  float m_part[4] = {-1e30f, -1e30f, -1e30f, -1e30f};
  float l_part[4] = {0.f, 0.f, 0.f, 0.f};

  const size_t kbase = (size_t)km * 576 * 256;

  // staging geometry (hi arrays only): 4 K-chunks + 4 V-chunks per thread
  int kdst[4], ksrc[4], vdst[4], vsrc[4];
#pragma unroll
  for (int i = 0; i < 4; ++i) {
    int ch = t + i * 256;
    int kr = ch >> 5, kc = ch & 31;
    kdst[i] = kr * 256 + (kc ^ (kr & 7)) * 8;
    ksrc[i] = kr * 256 + kc * 8;
    int dd = ch >> 2, vc = ch & 3;
    vdst[i] = dd * 32 + ((vc + (dd >> 1)) & 3) * 8;
    vsrc[i] = dd * 576 + vc * 8;
  }
  bf16x8 sKh[4], sVh[4];
#pragma unroll
  for (int i = 0; i < 4; ++i) {
    sKh[i] = *(const bf16x8*)(khi + kbase + ksrc[i]);
    sVh[i] = *(const bf16x8*)(vthi + kbase + vsrc[i]);
  }

  const int x0 = lr & 7;

  for (int kt = 0; kt < 18; ++kt) {
    const int j0 = kt * 32;
    // K-lo fragments (jt=0) direct from global — no LDS dependency.
    const u16* klb = klo + kbase + (size_t)j0 * 256;
    bf16x8 kl0[8];
#pragma unroll
    for (int s = 0; s < 8; ++s)
      kl0[s] = *(const bf16x8*)(klb + lr * 256 + s * 32 + lk * 8);

    __syncthreads();  // previous PV done reading LDS
#pragma unroll
    for (int i = 0; i < 4; ++i) {
      *(bf16x8*)(Kh + kdst[i]) = sKh[i];
      *(bf16x8*)(Vh + vdst[i]) = sVh[i];
    }
    if (kt < 17) {
      const int jn = j0 + 32;
#pragma unroll
      for (int i = 0; i < 4; ++i) {
        sKh[i] = *(const bf16x8*)(khi + kbase + (size_t)jn * 256 + ksrc[i]);
        sVh[i] = *(const bf16x8*)(vthi + kbase + jn + vsrc[i]);
      }
    }
    __syncthreads();  // K/V hi staged

    bf16x8 kl1[8];
#pragma unroll
    for (int s = 0; s < 8; ++s)
      kl1[s] = *(const bf16x8*)(klb + (16 + lr) * 256 + s * 32 + lk * 8);

    f32x4 s0 = {}, s1 = {};
    __builtin_amdgcn_s_setprio(1);
#pragma unroll
    for (int s = 0; s < 8; ++s) {
      int cl = s * 4 + lk;
      bf16x8 bh0 = *(const bf16x8*)(Kh + lr * 256 + (cl ^ x0) * 8);
      bf16x8 bh1 = *(const bf16x8*)(Kh + (lr + 16) * 256 + (cl ^ x0) * 8);
      s0 = MFMA16(qh[s], bh0, s0);
      s0 = MFMA16(qh[s], kl0[s], s0);
      s0 = MFMA16(ql[s], bh0, s0);
      s1 = MFMA16(qh[s], bh1, s1);
      s1 = MFMA16(qh[s], kl1[s], s1);
      s1 = MFMA16(ql[s], bh1, s1);
    }
    __builtin_amdgcn_s_setprio(0);

#pragma unroll
    for (int r = 0; r < 4; ++r) {
      float a0 = s0[r] * SCALE, a1 = s1[r] * SCALE;
      m_part[r] = fmaxf(m_part[r], fmaxf(a0, a1));
      float e0 = __expf(a0), e1 = __expf(a1);
      l_part[r] += e0 + e1;
      int prow = w * 16 + lk * 4 + r;
      u16 h0 = f2bf(e0);
      u16 h1 = f2bf(e1);
      Ph[prow * 40 + lr] = h0;
      Ph[prow * 40 + 16 + lr] = h1;
      Pl[prow * 40 + lr] = f2bf(e0 - bf2f(h0));
      Pl[prow * 40 + 16 + lr] = f2bf(e1 - bf2f(h1));
    }
    __syncthreads();  // P visible to all waves

    // PV, d-split: this wave covers d = w*64 .. w*64+63 for all 64 q.
    bf16x8 pah[4], pal[4];
#pragma unroll
    for (int qt = 0; qt < 4; ++qt) {
      pah[qt] = *(const bf16x8*)(Ph + (qt * 16 + lr) * 40 + lk * 8);
      pal[qt] = *(const bf16x8*)(Pl + (qt * 16 + lr) * 40 + lk * 8);
    }
    const u16* vlb = vtlo + kbase + j0;
    __builtin_amdgcn_s_setprio(1);
#pragma unroll
    for (int dt = 0; dt < 4; ++dt) {
      int d = w * 64 + dt * 16 + lr;
      int cp = (lk + (d >> 1)) & 3;
      bf16x8 vh_ = *(const bf16x8*)(Vh + d * 32 + cp * 8);
      bf16x8 vl_ = *(const bf16x8*)(vlb + (size_t)d * 576 + lk * 8);
#pragma unroll
      for (int qt = 0; qt < 4; ++qt) {
        o[qt][dt] = MFMA16(pah[qt], vh_, o[qt][dt]);
        o[qt][dt] = MFMA16(pah[qt], vl_, o[qt][dt]);
        o[qt][dt] = MFMA16(pal[qt], vh_, o[qt][dt]);
      }
    }
    __builtin_amdgcn_s_setprio(0);
  }

  // final stats reduction (per-wave owns q-tile w)
  float inv4[4], stat4[4];
#pragma unroll
  for (int r = 0; r < 4; ++r) {
    float lv = l_part[r], mv = m_part[r];
    lv += __shfl_xor(lv, 1, 64); mv = fmaxf(mv, __shfl_xor(mv, 1, 64));
    lv += __shfl_xor(lv, 2, 64); mv = fmaxf(mv, __shfl_xor(mv, 2, 64));
    lv += __shfl_xor(lv, 4, 64); mv = fmaxf(mv, __shfl_xor(mv, 4, 64));
    lv += __shfl_xor(lv, 8, 64); mv = fmaxf(mv, __shfl_xor(mv, 8, 64));
    inv4[r] = 1.0f / lv;
    stat4[r] = __expf(mv) * inv4[r];  // = 1/l_ref (softmax-normalized)
  }
  if (lr == 0) {
#pragma unroll
    for (int r = 0; r < 4; ++r) {
      invs[w * 16 + lk * 4 + r] = inv4[r];
      invl[(size_t)(b * 80 + km) * 576 + qw + lk * 4 + r] = stat4[r];
    }
  }
  __syncthreads();

  float* dst = rpartT + (size_t)(b * 80 + km) * (256 * 576);
#pragma unroll
  for (int qt = 0; qt < 4; ++qt) {
    float iv[4];
#pragma unroll
    for (int r = 0; r < 4; ++r) iv[r] = invs[qt * 16 + lk * 4 + r];
#pragma unroll
    for (int dt = 0; dt < 4; ++dt) {
      int d = w * 64 + dt * 16 + lr;
      f32x4 vv;
      vv[0] = o[qt][dt][0] * iv[0];
      vv[1] = o[qt][dt][1] * iv[1];
      vv[2] = o[qt][dt][2] * iv[2];
      vv[3] = o[qt][dt][3] * iv[3];
      *(f32x4*)(dst + (size_t)d * 576 + qb * 64 + qt * 16 + lk * 4) = vv;
    }
  }
}

// ---------------------------------------------------------------------------
// Weights: s[b,k,m] = mean_n 1/l_ref ; w = gate(p) * s / (sum_m s + 1e-8)
// ---------------------------------------------------------------------------
__global__ __launch_bounds__(256) void weight_kernel(const float* __restrict__ invl,
                                                     const float* __restrict__ p,
                                                     float* __restrict__ wout) {
  const int k = blockIdx.x, b = blockIdx.y;
  __shared__ float sm[10];
  __shared__ float red[4];
  const int t = threadIdx.x;
  for (int m = 0; m < 10; ++m) {
    float part = 0.f;
    for (int n = t; n < 576; n += 256)
      part += invl[(size_t)((b * 8 + k) * 10 + m) * 576 + n];
#pragma unroll
    for (int off = 32; off; off >>= 1) part += __shfl_down(part, off, 64);
    if ((t & 63) == 0) red[t >> 6] = part;
    __syncthreads();
    if (t == 0) sm[m] = (red[0] + red[1] + red[2] + red[3]) * (1.0f / 576.0f);
    __syncthreads();
  }
  if (t == 0) {
    float tot = 0.f;
    for (int m = 0; m < 10; ++m) tot += sm[m];
    float pmax = fmaxf(fmaxf(p[0 * 8 + k], p[1 * 8 + k]), fmaxf(p[2 * 8 + k], p[3 * 8 + k]));
    float gate = (pmax >= 0.01f) ? p[b * 8 + k] : 0.0f;
    for (int m = 0; m < 10; ++m)
      wout[(b * 8 + k) * 10 + m] = gate * sm[m] / (tot + 1e-8f);
  }
}

// ---------------------------------------------------------------------------
// out[b][d][n] = sum_km w[b,km] * rpartT[b,km][d][n]
// ---------------------------------------------------------------------------
__global__ __launch_bounds__(256) void reduce_out_k(const float* __restrict__ rpartT,
                                                    const float* __restrict__ wbuf,
                                                    float* __restrict__ out) {
  int idx = blockIdx.x * 256 + threadIdx.x;
  int b = idx / 147456;
  size_t off = (size_t)(idx % 147456);
  const float* base = rpartT + (size_t)b * 80 * 147456 + off;
  const float* wp = wbuf + b * 80;
  float acc = 0.f;
#pragma unroll 8
  for (int g = 0; g < 80; ++g) acc += wp[g] * base[(size_t)g * 147456];
  out[idx] = acc;
}

// ---------------------------------------------------------------------------
extern "C" void kernel_launch(void* const* d_in, const int* in_sizes, int n_in,
                              void* d_out, int out_size, void* d_ws, size_t ws_size,
                              hipStream_t stream) {
  const float* Q = (const float*)d_in[0];
  const float* dbk = (const float*)d_in[1];
  const float* dbv = (const float*)d_in[2];
  const float* p = (const float*)d_in[3];
  const float* Wq = (const float*)d_in[4];
  const float* Wk = (const float*)d_in[5];
  const float* Wv = (const float*)d_in[6];
  float* out = (float*)d_out;
  char* ws = (char*)d_ws;

  u16* qhi = (u16*)(ws);
  u16* qlo = (u16*)(ws + 1179648);
  u16* khi = (u16*)(ws + 2359296);
  u16* klo = (u16*)(ws + 25952256);
  u16* vthi = (u16*)(ws + 49545216);
  u16* vtlo = (u16*)(ws + 73138176);
  float* invl = (float*)(ws + 96731136);
  float* wbuf = (float*)(ws + 97468416);
  float* rpartT = (float*)(ws + 97469696);
  u16* wqh = (u16*)(ws + 97469696);
  u16* wql = wqh + 106496;
  u16* wkh = wql + 106496;
  u16* wkl = wkh + 106496;
  u16* wvh = wkl + 106496;
  u16* wvl = wvh + 98304;

  convert_w<<<1216, 256, 0, stream>>>(Wq, Wk, Wv, wqh, wql, wkh, wkl, wvh, wvl);
  proj_mfma<416, false><<<36, 256, 0, stream>>>(Q, wqh, wql, qhi, qlo);
  proj_mfma<416, false><<<720, 256, 0, stream>>>(dbk, wkh, wkl, khi, klo);
  proj_mfma<384, true><<<720, 256, 0, stream>>>(dbv, wvh, wvl, vthi, vtlo);
  attn_kernel<<<2880, 256, 0, stream>>>(qhi, qlo, khi, klo, vthi, vtlo, rpartT, invl);
  weight_kernel<<<dim3(8, 4), 256, 0, stream>>>(invl, p, wbuf);
  reduce_out_k<<<2304, 256, 0, stream>>>(rpartT, wbuf, out);
}

// Round 5
// 834.843 us; speedup vs baseline: 2.3911x; 2.3911x over previous
//
#include <hip/hip_runtime.h>

typedef float f32x4 __attribute__((ext_vector_type(4)));
typedef short bf16x8 __attribute__((ext_vector_type(8)));
typedef unsigned short u16;
typedef unsigned int u32;

#define SCALE 0.0625f
#define MFMA16(a, b, c) __builtin_amdgcn_mfma_f32_16x16x32_bf16((a), (b), (c), 0, 0, 0)

__device__ inline u16 f2bf(float x) {
  u32 u = __float_as_uint(x);
  u32 r = u + 0x7FFFu + ((u >> 16) & 1u);
  return (u16)(r >> 16);
}
__device__ inline float bf2f(u16 h) { return __uint_as_float(((u32)h) << 16); }

// async global->LDS, 16B per lane; lptr must be wave-uniform (dest = base + lane*16)
__device__ __forceinline__ void gld16(const void* g, void* l) {
  __builtin_amdgcn_global_load_lds(
      (const __attribute__((address_space(1))) unsigned int*)(uintptr_t)g,
      (__attribute__((address_space(3))) unsigned int*)(uintptr_t)l, 16, 0, 0);
}

// ---------------------------------------------------------------------------
// Transpose+split W matrices: W[k][n] fp32 -> Wt_hi/lo[n][k] bf16.
// ---------------------------------------------------------------------------
__global__ __launch_bounds__(256) void convert_w(
    const float* __restrict__ Wq, const float* __restrict__ Wk, const float* __restrict__ Wv,
    u16* __restrict__ qh, u16* __restrict__ qlo2, u16* __restrict__ kh, u16* __restrict__ klo2,
    u16* __restrict__ vh, u16* __restrict__ vlo2) {
  int idx = blockIdx.x * 256 + threadIdx.x;
  const float* src;
  u16 *dh, *dl;
  int KD;
  const int nq = 416 * 256;
  if (idx < nq) {
    src = Wq; dh = qh; dl = qlo2; KD = 416;
  } else if (idx < 2 * nq) {
    idx -= nq; src = Wk; dh = kh; dl = klo2; KD = 416;
  } else {
    idx -= 2 * nq;
    if (idx >= 384 * 256) return;
    src = Wv; dh = vh; dl = vlo2; KD = 384;
  }
  int k = idx >> 8, n = idx & 255;
  float x = src[idx];
  u16 h = f2bf(x);
  dh[n * KD + k] = h;
  dl[n * KD + k] = f2bf(x - bf2f(h));
}

// ---------------------------------------------------------------------------
// Projection GEMM, split-bf16 MFMA: C[m][256] = A[m][KD] @ W[KD][256].
// OUT=0: flat hi/lo [m][256] (Q).
// OUT=1: K into kvswz: per (km,kt) 32768-u16 block; Khi slot row*256+((c^(row&7))<<3)+e,
//        Klo at +8192.  (row=j&31, c=n>>3, e=n&7)
// OUT=2: V into kvswz: Vhi slot 16384 + d*32 + (((c+(d>>1))&3)<<3)+e, Vlo +8192.
//        (c = (j&31)>>3, e = j&7)
// ---------------------------------------------------------------------------
template <int KD, int OUT>
__global__ __launch_bounds__(256, 3) void proj_mfma(
    const float* __restrict__ A, const u16* __restrict__ wth, const u16* __restrict__ wtl,
    u16* __restrict__ oh, u16* __restrict__ ol) {
  __shared__ u16 Ah[64 * 32], Al[64 * 32];
  __shared__ u16 Wh[256 * 32], Wl[256 * 32];
  const int t = threadIdx.x;
  const int w = t >> 6, l = t & 63;
  const int lr = l & 15, lk = l >> 4;
  const int m0 = blockIdx.x * 64;
  f32x4 acc[16];
#pragma unroll
  for (int i = 0; i < 16; ++i) acc[i] = {};
  const int arow = t >> 2, ac = t & 3;
  const int acp = (ac + (arow >> 1)) & 3;
  for (int k0 = 0; k0 < KD; k0 += 32) {
    __syncthreads();
    {
      const float* s1 = A + (size_t)(m0 + arow) * KD + k0 + ac * 8;
      float4 f1 = *(const float4*)s1;
      float4 f2 = *(const float4*)(s1 + 4);
      float fs[8] = {f1.x, f1.y, f1.z, f1.w, f2.x, f2.y, f2.z, f2.w};
      bf16x8 hv, lv;
#pragma unroll
      for (int j = 0; j < 8; ++j) {
        u16 h = f2bf(fs[j]);
        hv[j] = (short)h;
        lv[j] = (short)f2bf(fs[j] - bf2f(h));
      }
      *(bf16x8*)(Ah + arow * 32 + acp * 8) = hv;
      *(bf16x8*)(Al + arow * 32 + acp * 8) = lv;
#pragma unroll
      for (int i = 0; i < 4; ++i) {
        int ch = t + i * 256;
        int n = ch >> 2, c = ch & 3;
        int cp = (c + (n >> 1)) & 3;
        *(bf16x8*)(Wh + n * 32 + cp * 8) = *(const bf16x8*)(wth + (size_t)n * KD + k0 + c * 8);
        *(bf16x8*)(Wl + n * 32 + cp * 8) = *(const bf16x8*)(wtl + (size_t)n * KD + k0 + c * 8);
      }
    }
    __syncthreads();
    const int row = w * 16 + lr;
    const int rcp = (lk + (row >> 1)) & 3;
    bf16x8 ah = *(const bf16x8*)(Ah + row * 32 + rcp * 8);
    bf16x8 al = *(const bf16x8*)(Al + row * 32 + rcp * 8);
#pragma unroll
    for (int fc = 0; fc < 16; ++fc) {
      int n = lr + 16 * fc;
      int cp = (lk + (n >> 1)) & 3;
      bf16x8 bh = *(const bf16x8*)(Wh + n * 32 + cp * 8);
      bf16x8 bl = *(const bf16x8*)(Wl + n * 32 + cp * 8);
      acc[fc] = MFMA16(ah, bh, acc[fc]);
      acc[fc] = MFMA16(ah, bl, acc[fc]);
      acc[fc] = MFMA16(al, bh, acc[fc]);
    }
  }
  if (OUT == 0) {
#pragma unroll
    for (int fc = 0; fc < 16; ++fc) {
      int n = lr + 16 * fc;
#pragma unroll
      for (int r = 0; r < 4; ++r) {
        int m = m0 + w * 16 + lk * 4 + r;
        float v = acc[fc][r];
        u16 h = f2bf(v);
        oh[(size_t)m * 256 + n] = h;
        ol[(size_t)m * 256 + n] = f2bf(v - bf2f(h));
      }
    }
  } else if (OUT == 1) {
#pragma unroll
    for (int r = 0; r < 4; ++r) {
      int m = m0 + w * 16 + lk * 4 + r;
      int km = m / 576;
      int j = m - km * 576;
      int kt = j >> 5, row = j & 31;
      size_t rowbase = ((size_t)(km * 18 + kt) << 15) + (row << 8);
      int rx = row & 7;
#pragma unroll
      for (int fc = 0; fc < 16; ++fc) {
        int c = (lr >> 3) + 2 * fc;
        size_t slot = rowbase + (size_t)(((c ^ rx) << 3) + (lr & 7));
        float v = acc[fc][r];
        u16 h = f2bf(v);
        oh[slot] = h;
        oh[slot + 8192] = f2bf(v - bf2f(h));
      }
    }
  } else {
    const int km = m0 / 576;
    const int j0 = (m0 % 576) + w * 16 + lk * 4;
    const int kt = j0 >> 5;
    const int jl = j0 & 31;
    const int c = jl >> 3, e0 = jl & 7;
    const size_t vbase = ((size_t)(km * 18 + kt) << 15) + 16384;
#pragma unroll
    for (int fc = 0; fc < 16; ++fc) {
      int n = lr + 16 * fc;  // d
      int cp = (c + (n >> 1)) & 3;
      size_t slot = vbase + (size_t)((n << 5) + (cp << 3) + e0);
      u16 hs[4], ls[4];
#pragma unroll
      for (int r = 0; r < 4; ++r) {
        float v = acc[fc][r];
        u16 h = f2bf(v);
        hs[r] = h;
        ls[r] = f2bf(v - bf2f(h));
      }
      *(ushort4*)(oh + slot) = make_ushort4(hs[0], hs[1], hs[2], hs[3]);
      *(ushort4*)(oh + slot + 8192) = make_ushort4(ls[0], ls[1], ls[2], ls[3]);
    }
  }
}

// ---------------------------------------------------------------------------
// Flash attention, 512 threads / 8 waves per block, q=64 per block.
// QK^T: waves = (wq 0..3) x (wk 0..1): 16q x 16keys each.
// PV: d-split, wave w covers d = w*32..w*32+31 for all 64 q (P shared in LDS).
// K/V tiles staged via global_load_lds from pre-swizzled kvswz (one 64KB
// linear block per (km,kt)).  m==0 softmax, stats reduced once at end.
// ---------------------------------------------------------------------------
__global__ __launch_bounds__(512, 4) void attn_kernel(
    const u16* __restrict__ qhi, const u16* __restrict__ qlo,
    const u16* __restrict__ kvswz,
    float* __restrict__ rpartT, float* __restrict__ invl) {
  __shared__ u16 KV[32768];  // [Kh 8192][Kl 8192][Vh 8192][Vl 8192] (u16 units)
  __shared__ u16 Ph[64 * 40], Pl[64 * 40];
  __shared__ float lred[2][64], mred[2][64];
  __shared__ float invs[64];
  const int t = threadIdx.x;
  const int w = t >> 6, l = t & 63;
  const int lr = l & 15, lk = l >> 4;
  const int wq = w >> 1, wk = w & 1;
  // XCD-cluster swizzle: all 360 blocks of km%8==xcd land on one XCD stream.
  const int L = blockIdx.x;
  const int xcd = L & 7, slot = L >> 3;
  const int km = xcd + 8 * (slot / 36);
  const int inner = slot % 36;
  const int b = inner & 3, qb = inner >> 2;

  // Q fragments: rows qb*64 + wq*16 + lr, k-chunks lk*8 + s*32
  bf16x8 qh[8], ql[8];
  {
    const size_t qoff = ((size_t)(b * 576 + qb * 64 + wq * 16 + lr)) * 256 + lk * 8;
    const u16* ph = qhi + qoff;
    const u16* pl = qlo + qoff;
#pragma unroll
    for (int s = 0; s < 8; ++s) {
      qh[s] = *(const bf16x8*)(ph + s * 32);
      ql[s] = *(const bf16x8*)(pl + s * 32);
    }
  }

  f32x4 o[4][2];
#pragma unroll
  for (int i = 0; i < 4; ++i)
#pragma unroll
    for (int j = 0; j < 2; ++j) o[i][j] = {};
  float m_part[4] = {-1e30f, -1e30f, -1e30f, -1e30f};
  float l_part[4] = {0.f, 0.f, 0.f, 0.f};

  const char* kvb = (const char*)kvswz + (size_t)(km * 18) * 65536;
  char* lbase = (char*)&KV[0] + (size_t)w * 1024;
  const int krow = wk * 16 + lr;
  const int kx = lr & 7;

  for (int kt = 0; kt < 18; ++kt) {
    __syncthreads();  // previous kt's QK/PV LDS reads complete
    {
      const char* src = kvb + (size_t)kt * 65536 + t * 16;
#pragma unroll
      for (int i = 0; i < 8; ++i) gld16(src + i * 8192, lbase + i * 8192);
    }
    __syncthreads();  // staging DMA complete (compiler drains vmcnt)

    // ---- QK^T: 16q x 16keys per wave ----
    f32x4 s0 = {};
    __builtin_amdgcn_s_setprio(1);
#pragma unroll
    for (int s = 0; s < 8; ++s) {
      int c = ((s * 4 + lk) ^ kx) * 8;
      bf16x8 bh = *(const bf16x8*)(KV + krow * 256 + c);
      bf16x8 bl = *(const bf16x8*)(KV + 8192 + krow * 256 + c);
      s0 = MFMA16(qh[s], bh, s0);
      s0 = MFMA16(qh[s], bl, s0);
      s0 = MFMA16(ql[s], bh, s0);
    }
    __builtin_amdgcn_s_setprio(0);

    // ---- P = exp(S*scale), stats, write P hi/lo to LDS ----
#pragma unroll
    for (int r = 0; r < 4; ++r) {
      float a = s0[r] * SCALE;
      m_part[r] = fmaxf(m_part[r], a);
      float e = __expf(a);
      l_part[r] += e;
      u16 h = f2bf(e);
      int prow = wq * 16 + lk * 4 + r;
      Ph[prow * 40 + wk * 16 + lr] = h;
      Pl[prow * 40 + wk * 16 + lr] = f2bf(e - bf2f(h));
    }
    __syncthreads();  // P visible to all waves

    // ---- PV: wave w covers d = w*32 + dt*16 + lr ----
    __builtin_amdgcn_s_setprio(1);
#pragma unroll
    for (int dt = 0; dt < 2; ++dt) {
      int d = w * 32 + dt * 16 + lr;
      int cp = ((lk + (d >> 1)) & 3) * 8;
      bf16x8 vh = *(const bf16x8*)(KV + 16384 + d * 32 + cp);
      bf16x8 vl = *(const bf16x8*)(KV + 24576 + d * 32 + cp);
#pragma unroll
      for (int qt = 0; qt < 4; ++qt) {
        bf16x8 pah = *(const bf16x8*)(Ph + (qt * 16 + lr) * 40 + lk * 8);
        bf16x8 pal = *(const bf16x8*)(Pl + (qt * 16 + lr) * 40 + lk * 8);
        o[qt][dt] = MFMA16(pah, vh, o[qt][dt]);
        o[qt][dt] = MFMA16(pah, vl, o[qt][dt]);
        o[qt][dt] = MFMA16(pal, vh, o[qt][dt]);
      }
    }
    __builtin_amdgcn_s_setprio(0);
  }

  // ---- stats: reduce over this wave's 16 keys, then combine wk halves ----
#pragma unroll
  for (int r = 0; r < 4; ++r) {
    float lv = l_part[r], mv = m_part[r];
    lv += __shfl_xor(lv, 1, 64); mv = fmaxf(mv, __shfl_xor(mv, 1, 64));
    lv += __shfl_xor(lv, 2, 64); mv = fmaxf(mv, __shfl_xor(mv, 2, 64));
    lv += __shfl_xor(lv, 4, 64); mv = fmaxf(mv, __shfl_xor(mv, 4, 64));
    lv += __shfl_xor(lv, 8, 64); mv = fmaxf(mv, __shfl_xor(mv, 8, 64));
    if (lr == 0) {
      lred[wk][wq * 16 + lk * 4 + r] = lv;
      mred[wk][wq * 16 + lk * 4 + r] = mv;
    }
  }
  __syncthreads();
  if (w == 0) {
    float ls = lred[0][l] + lred[1][l];
    float mv = fmaxf(mred[0][l], mred[1][l]);
    invs[l] = 1.0f / ls;
    invl[(size_t)(b * 80 + km) * 576 + qb * 64 + l] = __expf(mv) / ls;
  }
  __syncthreads();

  float* dst = rpartT + (size_t)(b * 80 + km) * 147456;
#pragma unroll
  for (int qt = 0; qt < 4; ++qt) {
    float iv[4];
#pragma unroll
    for (int r = 0; r < 4; ++r) iv[r] = invs[qt * 16 + lk * 4 + r];
#pragma unroll
    for (int dt = 0; dt < 2; ++dt) {
      int d = w * 32 + dt * 16 + lr;
      f32x4 vv;
      vv[0] = o[qt][dt][0] * iv[0];
      vv[1] = o[qt][dt][1] * iv[1];
      vv[2] = o[qt][dt][2] * iv[2];
      vv[3] = o[qt][dt][3] * iv[3];
      *(f32x4*)(dst + (size_t)d * 576 + qb * 64 + qt * 16 + lk * 4) = vv;
    }
  }
}

// ---------------------------------------------------------------------------
// Weights: s[b,k,m] = mean_n 1/l_ref ; w = gate(p) * s / (sum_m s + 1e-8)
// ---------------------------------------------------------------------------
__global__ __launch_bounds__(256) void weight_kernel(const float* __restrict__ invl,
                                                     const float* __restrict__ p,
                                                     float* __restrict__ wout) {
  const int k = blockIdx.x, b = blockIdx.y;
  __shared__ float sm[10];
  __shared__ float red[4];
  const int t = threadIdx.x;
  for (int m = 0; m < 10; ++m) {
    float part = 0.f;
    for (int n = t; n < 576; n += 256)
      part += invl[(size_t)((b * 8 + k) * 10 + m) * 576 + n];
#pragma unroll
    for (int off = 32; off; off >>= 1) part += __shfl_down(part, off, 64);
    if ((t & 63) == 0) red[t >> 6] = part;
    __syncthreads();
    if (t == 0) sm[m] = (red[0] + red[1] + red[2] + red[3]) * (1.0f / 576.0f);
    __syncthreads();
  }
  if (t == 0) {
    float tot = 0.f;
    for (int m = 0; m < 10; ++m) tot += sm[m];
    float pmax = fmaxf(fmaxf(p[0 * 8 + k], p[1 * 8 + k]), fmaxf(p[2 * 8 + k], p[3 * 8 + k]));
    float gate = (pmax >= 0.01f) ? p[b * 8 + k] : 0.0f;
    for (int m = 0; m < 10; ++m)
      wout[(b * 8 + k) * 10 + m] = gate * sm[m] / (tot + 1e-8f);
  }
}

// ---------------------------------------------------------------------------
// out[b][d][n] = sum_km w[b,km] * rpartT[b,km][d][n]
// ---------------------------------------------------------------------------
__global__ __launch_bounds__(256) void reduce_out_k(const float* __restrict__ rpartT,
                                                    const float* __restrict__ wbuf,
                                                    float* __restrict__ out) {
  int idx = blockIdx.x * 256 + threadIdx.x;
  int b = idx / 147456;
  size_t off = (size_t)(idx % 147456);
  const float* base = rpartT + (size_t)b * 80 * 147456 + off;
  const float* wp = wbuf + b * 80;
  float acc = 0.f;
#pragma unroll 8
  for (int g = 0; g < 80; ++g) acc += wp[g] * base[(size_t)g * 147456];
  out[idx] = acc;
}

// ---------------------------------------------------------------------------
extern "C" void kernel_launch(void* const* d_in, const int* in_sizes, int n_in,
                              void* d_out, int out_size, void* d_ws, size_t ws_size,
                              hipStream_t stream) {
  const float* Q = (const float*)d_in[0];
  const float* dbk = (const float*)d_in[1];
  const float* dbv = (const float*)d_in[2];
  const float* p = (const float*)d_in[3];
  const float* Wq = (const float*)d_in[4];
  const float* Wk = (const float*)d_in[5];
  const float* Wv = (const float*)d_in[6];
  float* out = (float*)d_out;
  char* ws = (char*)d_ws;

  u16* qhi = (u16*)(ws);                    // 1,179,648 B
  u16* qlo = (u16*)(ws + 1179648);          // 1,179,648 B
  u16* kvswz = (u16*)(ws + 2359296);        // 80*18*65536 = 94,371,840 B
  float* invl = (float*)(ws + 96731136);    // 737,280 B
  float* wbuf = (float*)(ws + 97468416);    // 1,280 B
  float* rpartT = (float*)(ws + 97469696);  // 188,743,680 B
  // W^T hi/lo temporaries aliased into rpartT region (consumed before attn writes)
  u16* wqh = (u16*)(ws + 97469696);
  u16* wql = wqh + 106496;
  u16* wkh = wql + 106496;
  u16* wkl = wkh + 106496;
  u16* wvh = wkl + 106496;
  u16* wvl = wvh + 98304;

  convert_w<<<1216, 256, 0, stream>>>(Wq, Wk, Wv, wqh, wql, wkh, wkl, wvh, wvl);
  proj_mfma<416, 0><<<36, 256, 0, stream>>>(Q, wqh, wql, qhi, qlo);
  proj_mfma<416, 1><<<720, 256, 0, stream>>>(dbk, wkh, wkl, kvswz, nullptr);
  proj_mfma<384, 2><<<720, 256, 0, stream>>>(dbv, wvh, wvl, kvswz, nullptr);
  attn_kernel<<<2880, 512, 0, stream>>>(qhi, qlo, kvswz, rpartT, invl);
  weight_kernel<<<dim3(8, 4), 256, 0, stream>>>(invl, p, wbuf);
  reduce_out_k<<<2304, 256, 0, stream>>>(rpartT, wbuf, out);
}

// Round 6
// 818.485 us; speedup vs baseline: 2.4389x; 1.0200x over previous
//
#include <hip/hip_runtime.h>

typedef float f32x4 __attribute__((ext_vector_type(4)));
typedef short bf16x8 __attribute__((ext_vector_type(8)));
typedef unsigned short u16;
typedef unsigned int u32;

#define SCALE 0.0625f
#define MFMA16(a, b, c) __builtin_amdgcn_mfma_f32_16x16x32_bf16((a), (b), (c), 0, 0, 0)

__device__ inline u16 f2bf(float x) {
  u32 u = __float_as_uint(x);
  u32 r = u + 0x7FFFu + ((u >> 16) & 1u);
  return (u16)(r >> 16);
}
__device__ inline float bf2f(u16 h) { return __uint_as_float(((u32)h) << 16); }

// async global->LDS, 16B per lane; LDS dest is wave-uniform base + lane*16
__device__ __forceinline__ void gld16(const void* g, void* l) {
  __builtin_amdgcn_global_load_lds(
      (const __attribute__((address_space(1))) unsigned int*)(uintptr_t)g,
      (__attribute__((address_space(3))) unsigned int*)(uintptr_t)l, 16, 0, 0);
}

// ---------------------------------------------------------------------------
// Transpose+split W matrices: W[k][n] fp32 -> Wt_hi/lo[n][k] bf16.
// ---------------------------------------------------------------------------
__global__ __launch_bounds__(256) void convert_w(
    const float* __restrict__ Wq, const float* __restrict__ Wk, const float* __restrict__ Wv,
    u16* __restrict__ qh, u16* __restrict__ qlo2, u16* __restrict__ kh, u16* __restrict__ klo2,
    u16* __restrict__ vh, u16* __restrict__ vlo2) {
  int idx = blockIdx.x * 256 + threadIdx.x;
  const float* src;
  u16 *dh, *dl;
  int KD;
  const int nq = 416 * 256;
  if (idx < nq) {
    src = Wq; dh = qh; dl = qlo2; KD = 416;
  } else if (idx < 2 * nq) {
    idx -= nq; src = Wk; dh = kh; dl = klo2; KD = 416;
  } else {
    idx -= 2 * nq;
    if (idx >= 384 * 256) return;
    src = Wv; dh = vh; dl = vlo2; KD = 384;
  }
  int k = idx >> 8, n = idx & 255;
  float x = src[idx];
  u16 h = f2bf(x);
  dh[n * KD + k] = h;
  dl[n * KD + k] = f2bf(x - bf2f(h));
}

// ---------------------------------------------------------------------------
// Projection GEMM, split-bf16 MFMA: C[m][256] = A[m][KD] @ W[KD][256].
// OUT=0: flat hi/lo [m][256] (Q).
// OUT=1: K into kvswz pre-swizzled LDS image.
// OUT=2: V into kvswz pre-swizzled LDS image (V^T).
// ---------------------------------------------------------------------------
template <int KD, int OUT>
__global__ __launch_bounds__(256, 3) void proj_mfma(
    const float* __restrict__ A, const u16* __restrict__ wth, const u16* __restrict__ wtl,
    u16* __restrict__ oh, u16* __restrict__ ol) {
  __shared__ u16 Ah[64 * 32], Al[64 * 32];
  __shared__ u16 Wh[256 * 32], Wl[256 * 32];
  const int t = threadIdx.x;
  const int w = t >> 6, l = t & 63;
  const int lr = l & 15, lk = l >> 4;
  const int m0 = blockIdx.x * 64;
  f32x4 acc[16];
#pragma unroll
  for (int i = 0; i < 16; ++i) acc[i] = {};
  const int arow = t >> 2, ac = t & 3;
  const int acp = (ac + (arow >> 1)) & 3;
  for (int k0 = 0; k0 < KD; k0 += 32) {
    __syncthreads();
    {
      const float* s1 = A + (size_t)(m0 + arow) * KD + k0 + ac * 8;
      float4 f1 = *(const float4*)s1;
      float4 f2 = *(const float4*)(s1 + 4);
      float fs[8] = {f1.x, f1.y, f1.z, f1.w, f2.x, f2.y, f2.z, f2.w};
      bf16x8 hv, lv;
#pragma unroll
      for (int j = 0; j < 8; ++j) {
        u16 h = f2bf(fs[j]);
        hv[j] = (short)h;
        lv[j] = (short)f2bf(fs[j] - bf2f(h));
      }
      *(bf16x8*)(Ah + arow * 32 + acp * 8) = hv;
      *(bf16x8*)(Al + arow * 32 + acp * 8) = lv;
#pragma unroll
      for (int i = 0; i < 4; ++i) {
        int ch = t + i * 256;
        int n = ch >> 2, c = ch & 3;
        int cp = (c + (n >> 1)) & 3;
        *(bf16x8*)(Wh + n * 32 + cp * 8) = *(const bf16x8*)(wth + (size_t)n * KD + k0 + c * 8);
        *(bf16x8*)(Wl + n * 32 + cp * 8) = *(const bf16x8*)(wtl + (size_t)n * KD + k0 + c * 8);
      }
    }
    __syncthreads();
    const int row = w * 16 + lr;
    const int rcp = (lk + (row >> 1)) & 3;
    bf16x8 ah = *(const bf16x8*)(Ah + row * 32 + rcp * 8);
    bf16x8 al = *(const bf16x8*)(Al + row * 32 + rcp * 8);
#pragma unroll
    for (int fc = 0; fc < 16; ++fc) {
      int n = lr + 16 * fc;
      int cp = (lk + (n >> 1)) & 3;
      bf16x8 bh = *(const bf16x8*)(Wh + n * 32 + cp * 8);
      bf16x8 bl = *(const bf16x8*)(Wl + n * 32 + cp * 8);
      acc[fc] = MFMA16(ah, bh, acc[fc]);
      acc[fc] = MFMA16(ah, bl, acc[fc]);
      acc[fc] = MFMA16(al, bh, acc[fc]);
    }
  }
  if (OUT == 0) {
#pragma unroll
    for (int fc = 0; fc < 16; ++fc) {
      int n = lr + 16 * fc;
#pragma unroll
      for (int r = 0; r < 4; ++r) {
        int m = m0 + w * 16 + lk * 4 + r;
        float v = acc[fc][r];
        u16 h = f2bf(v);
        oh[(size_t)m * 256 + n] = h;
        ol[(size_t)m * 256 + n] = f2bf(v - bf2f(h));
      }
    }
  } else if (OUT == 1) {
#pragma unroll
    for (int r = 0; r < 4; ++r) {
      int m = m0 + w * 16 + lk * 4 + r;
      int km = m / 576;
      int j = m - km * 576;
      int kt = j >> 5, row = j & 31;
      size_t rowbase = ((size_t)(km * 18 + kt) << 15) + (row << 8);
      int rx = row & 7;
#pragma unroll
      for (int fc = 0; fc < 16; ++fc) {
        int c = (lr >> 3) + 2 * fc;
        size_t slot = rowbase + (size_t)(((c ^ rx) << 3) + (lr & 7));
        float v = acc[fc][r];
        u16 h = f2bf(v);
        oh[slot] = h;
        oh[slot + 8192] = f2bf(v - bf2f(h));
      }
    }
  } else {
    const int km = m0 / 576;
    const int j0 = (m0 % 576) + w * 16 + lk * 4;
    const int kt = j0 >> 5;
    const int jl = j0 & 31;
    const int c = jl >> 3, e0 = jl & 7;
    const size_t vbase = ((size_t)(km * 18 + kt) << 15) + 16384;
#pragma unroll
    for (int fc = 0; fc < 16; ++fc) {
      int n = lr + 16 * fc;  // d
      int cp = (c + (n >> 1)) & 3;
      size_t slot = vbase + (size_t)((n << 5) + (cp << 3) + e0);
      u16 hs[4], ls[4];
#pragma unroll
      for (int r = 0; r < 4; ++r) {
        float v = acc[fc][r];
        u16 h = f2bf(v);
        hs[r] = h;
        ls[r] = f2bf(v - bf2f(h));
      }
      *(ushort4*)(oh + slot) = make_ushort4(hs[0], hs[1], hs[2], hs[3]);
      *(ushort4*)(oh + slot + 8192) = make_ushort4(ls[0], ls[1], ls[2], ls[3]);
    }
  }
}

// ---------------------------------------------------------------------------
// Flash attention, 512 threads / 8 waves, q=64/block, keys 32/kt.
// Swapped QK^T: S^T = mfma(K_frag, Q_frag) -> lane holds 4 consecutive keys
// of one q row; P hi/lo written as single b64 stores.  m==0 softmax.
// Pipelined staging (counted vmcnt): V(kt) flies under QK(kt); K(kt+1)
// issued after P-barrier, flies under PV(kt); V(kt+1) after PV-barrier.
// ---------------------------------------------------------------------------
__global__ __launch_bounds__(512, 4) void attn_kernel(
    const u16* __restrict__ qhi, const u16* __restrict__ qlo,
    const u16* __restrict__ kvswz,
    float* __restrict__ rpartT, float* __restrict__ invl) {
  __shared__ u16 KV[32768];  // [Kh 8192][Kl 8192][Vh 8192][Vl 8192] (u16 units)
  __shared__ u16 Ph[64 * 40], Pl[64 * 40];
  __shared__ float lred[2][64], mred[2][64];
  __shared__ float invs[64];
  const int t = threadIdx.x;
  const int w = t >> 6, l = t & 63;
  const int lr = l & 15, lk = l >> 4;
  const int wq = w >> 1, wk = w & 1;
  const int L = blockIdx.x;
  const int xcd = L & 7, slot = L >> 3;
  const int km = xcd + 8 * (slot / 36);
  const int inner = slot % 36;
  const int b = inner & 3, qb = inner >> 2;

  // Q fragments (serve as MFMA B-operand: col=q=lr, k-chunk=lk)
  bf16x8 qh[8], ql[8];
  {
    const size_t qoff = ((size_t)(b * 576 + qb * 64 + wq * 16 + lr)) * 256 + lk * 8;
    const u16* ph = qhi + qoff;
    const u16* pl = qlo + qoff;
#pragma unroll
    for (int s = 0; s < 8; ++s) {
      qh[s] = *(const bf16x8*)(ph + s * 32);
      ql[s] = *(const bf16x8*)(pl + s * 32);
    }
  }

  f32x4 o[4][2];
#pragma unroll
  for (int i = 0; i < 4; ++i)
#pragma unroll
    for (int j = 0; j < 2; ++j) o[i][j] = {};
  float m_part = -1e30f, l_part = 0.f;  // per-lane, q = wq*16+lr

  const char* kvb = (const char*)kvswz + (size_t)(km * 18) * 65536;
  char* lbase = (char*)&KV[0] + (size_t)w * 1024;
  const int srcoff = t * 16;

  // prologue: issue K(0) then V(0); wait K; barrier.  (V stays in flight)
  {
    const char* src = kvb + srcoff;
#pragma unroll
    for (int i = 0; i < 4; ++i) gld16(src + i * 8192, lbase + i * 8192);
    __builtin_amdgcn_sched_barrier(0);
#pragma unroll
    for (int i = 4; i < 8; ++i) gld16(src + i * 8192, lbase + i * 8192);
  }
  asm volatile("s_waitcnt vmcnt(4)" ::: "memory");
  __builtin_amdgcn_sched_barrier(0);
  __builtin_amdgcn_s_barrier();
  __builtin_amdgcn_sched_barrier(0);

  const int krow = wk * 16 + lr;
  const int kx = lr & 7;

  for (int kt = 0; kt < 18; ++kt) {
    // ---- QK^T (swapped): wave computes S^T[16 keys][16 q]; V(kt) in flight
    f32x4 s0 = {};
    __builtin_amdgcn_s_setprio(1);
#pragma unroll
    for (int s = 0; s < 8; ++s) {
      int c = ((s * 4 + lk) ^ kx) * 8;
      bf16x8 khf = *(const bf16x8*)(KV + krow * 256 + c);
      bf16x8 klf = *(const bf16x8*)(KV + 8192 + krow * 256 + c);
      s0 = MFMA16(khf, qh[s], s0);
      s0 = MFMA16(klf, qh[s], s0);
      s0 = MFMA16(khf, ql[s], s0);
    }
    __builtin_amdgcn_s_setprio(0);

    // ---- P = exp(S*scale): lane holds keys lk*4..+3 for q=wq*16+lr
    ushort4 ph4, pl4;
#pragma unroll
    for (int r = 0; r < 4; ++r) {
      float a = s0[r] * SCALE;
      m_part = fmaxf(m_part, a);
      float e = __expf(a);
      l_part += e;
      u16 h = f2bf(e);
      (&ph4.x)[r] = h;
      (&pl4.x)[r] = f2bf(e - bf2f(h));
    }
    {
      int poff = (wq * 16 + lr) * 40 + wk * 16 + lk * 4;
      *(ushort4*)(Ph + poff) = ph4;
      *(ushort4*)(Pl + poff) = pl4;
    }
    asm volatile("s_waitcnt lgkmcnt(0)" ::: "memory");  // P written, K reads done
    asm volatile("s_waitcnt vmcnt(0)" ::: "memory");    // V(kt) resident
    __builtin_amdgcn_sched_barrier(0);
    __builtin_amdgcn_s_barrier();  // B1: P + V visible; K region free
    __builtin_amdgcn_sched_barrier(0);

    // ---- issue K(kt+1) DMA (flies under PV)
    {
      int ktn = kt < 17 ? kt + 1 : 17;
      const char* src = kvb + (size_t)ktn * 65536 + srcoff;
#pragma unroll
      for (int i = 0; i < 4; ++i) gld16(src + i * 8192, lbase + i * 8192);
    }
    __builtin_amdgcn_sched_barrier(0);

    // ---- PV: wave covers d = w*32 .. +31 for all 64 q
    __builtin_amdgcn_s_setprio(1);
#pragma unroll
    for (int dt = 0; dt < 2; ++dt) {
      int d = w * 32 + dt * 16 + lr;
      int cp = ((lk + (d >> 1)) & 3) * 8;
      bf16x8 vh = *(const bf16x8*)(KV + 16384 + d * 32 + cp);
      bf16x8 vl = *(const bf16x8*)(KV + 24576 + d * 32 + cp);
#pragma unroll
      for (int qt = 0; qt < 4; ++qt) {
        bf16x8 pah = *(const bf16x8*)(Ph + (qt * 16 + lr) * 40 + lk * 8);
        bf16x8 pal = *(const bf16x8*)(Pl + (qt * 16 + lr) * 40 + lk * 8);
        o[qt][dt] = MFMA16(pah, vh, o[qt][dt]);
        o[qt][dt] = MFMA16(pah, vl, o[qt][dt]);
        o[qt][dt] = MFMA16(pal, vh, o[qt][dt]);
      }
    }
    __builtin_amdgcn_s_setprio(0);
    asm volatile("s_waitcnt lgkmcnt(0)" ::: "memory");  // V/P reads done
    __builtin_amdgcn_sched_barrier(0);
    __builtin_amdgcn_s_barrier();  // B2: V region free
    __builtin_amdgcn_sched_barrier(0);

    // ---- issue V(kt+1) DMA; wait K(kt+1); barrier
    {
      int ktn = kt < 17 ? kt + 1 : 17;
      const char* src = kvb + (size_t)ktn * 65536 + srcoff;
#pragma unroll
      for (int i = 4; i < 8; ++i) gld16(src + i * 8192, lbase + i * 8192);
    }
    asm volatile("s_waitcnt vmcnt(4)" ::: "memory");  // K(kt+1) resident
    __builtin_amdgcn_sched_barrier(0);
    __builtin_amdgcn_s_barrier();  // B3
    __builtin_amdgcn_sched_barrier(0);
  }

  // ---- stats: lane q=wq*16+lr; combine lk groups then wk halves
  {
    float lv = l_part, mv = m_part;
    lv += __shfl_xor(lv, 16, 64);
    mv = fmaxf(mv, __shfl_xor(mv, 16, 64));
    lv += __shfl_xor(lv, 32, 64);
    mv = fmaxf(mv, __shfl_xor(mv, 32, 64));
    if (l < 16) {
      lred[wk][wq * 16 + l] = lv;
      mred[wk][wq * 16 + l] = mv;
    }
  }
  __syncthreads();
  if (w == 0) {
    float ls = lred[0][l] + lred[1][l];
    float mv = fmaxf(mred[0][l], mred[1][l]);
    invs[l] = 1.0f / ls;
    invl[(size_t)(b * 80 + km) * 576 + qb * 64 + l] = __expf(mv) / ls;
  }
  __syncthreads();

  float* dst = rpartT + (size_t)(b * 80 + km) * 147456;
#pragma unroll
  for (int qt = 0; qt < 4; ++qt) {
    float iv[4];
#pragma unroll
    for (int r = 0; r < 4; ++r) iv[r] = invs[qt * 16 + lk * 4 + r];
#pragma unroll
    for (int dt = 0; dt < 2; ++dt) {
      int d = w * 32 + dt * 16 + lr;
      f32x4 vv;
      vv[0] = o[qt][dt][0] * iv[0];
      vv[1] = o[qt][dt][1] * iv[1];
      vv[2] = o[qt][dt][2] * iv[2];
      vv[3] = o[qt][dt][3] * iv[3];
      *(f32x4*)(dst + (size_t)d * 576 + qb * 64 + qt * 16 + lk * 4) = vv;
    }
  }
}

// ---------------------------------------------------------------------------
// Weights: s[b,k,m] = mean_n 1/l_ref ; w = gate(p) * s / (sum_m s + 1e-8)
// ---------------------------------------------------------------------------
__global__ __launch_bounds__(256) void weight_kernel(const float* __restrict__ invl,
                                                     const float* __restrict__ p,
                                                     float* __restrict__ wout) {
  const int k = blockIdx.x, b = blockIdx.y;
  __shared__ float sm[10];
  __shared__ float red[4];
  const int t = threadIdx.x;
  for (int m = 0; m < 10; ++m) {
    float part = 0.f;
    for (int n = t; n < 576; n += 256)
      part += invl[(size_t)((b * 8 + k) * 10 + m) * 576 + n];
#pragma unroll
    for (int off = 32; off; off >>= 1) part += __shfl_down(part, off, 64);
    if ((t & 63) == 0) red[t >> 6] = part;
    __syncthreads();
    if (t == 0) sm[m] = (red[0] + red[1] + red[2] + red[3]) * (1.0f / 576.0f);
    __syncthreads();
  }
  if (t == 0) {
    float tot = 0.f;
    for (int m = 0; m < 10; ++m) tot += sm[m];
    float pmax = fmaxf(fmaxf(p[0 * 8 + k], p[1 * 8 + k]), fmaxf(p[2 * 8 + k], p[3 * 8 + k]));
    float gate = (pmax >= 0.01f) ? p[b * 8 + k] : 0.0f;
    for (int m = 0; m < 10; ++m)
      wout[(b * 8 + k) * 10 + m] = gate * sm[m] / (tot + 1e-8f);
  }
}

// ---------------------------------------------------------------------------
// out[b][d][n] = sum_km w[b,km] * rpartT[b,km][d][n]
// ---------------------------------------------------------------------------
__global__ __launch_bounds__(256) void reduce_out_k(const float* __restrict__ rpartT,
                                                    const float* __restrict__ wbuf,
                                                    float* __restrict__ out) {
  int idx = blockIdx.x * 256 + threadIdx.x;
  int b = idx / 147456;
  size_t off = (size_t)(idx % 147456);
  const float* base = rpartT + (size_t)b * 80 * 147456 + off;
  const float* wp = wbuf + b * 80;
  float acc = 0.f;
#pragma unroll 8
  for (int g = 0; g < 80; ++g) acc += wp[g] * base[(size_t)g * 147456];
  out[idx] = acc;
}

// ---------------------------------------------------------------------------
extern "C" void kernel_launch(void* const* d_in, const int* in_sizes, int n_in,
                              void* d_out, int out_size, void* d_ws, size_t ws_size,
                              hipStream_t stream) {
  const float* Q = (const float*)d_in[0];
  const float* dbk = (const float*)d_in[1];
  const float* dbv = (const float*)d_in[2];
  const float* p = (const float*)d_in[3];
  const float* Wq = (const float*)d_in[4];
  const float* Wk = (const float*)d_in[5];
  const float* Wv = (const float*)d_in[6];
  float* out = (float*)d_out;
  char* ws = (char*)d_ws;

  u16* qhi = (u16*)(ws);                    // 1,179,648 B
  u16* qlo = (u16*)(ws + 1179648);          // 1,179,648 B
  u16* kvswz = (u16*)(ws + 2359296);        // 80*18*65536 = 94,371,840 B
  float* invl = (float*)(ws + 96731136);    // 737,280 B
  float* wbuf = (float*)(ws + 97468416);    // 1,280 B
  float* rpartT = (float*)(ws + 97469696);  // 188,743,680 B
  // W^T hi/lo temporaries aliased into rpartT region (consumed before attn writes)
  u16* wqh = (u16*)(ws + 97469696);
  u16* wql = wqh + 106496;
  u16* wkh = wql + 106496;
  u16* wkl = wkh + 106496;
  u16* wvh = wkl + 106496;
  u16* wvl = wvh + 98304;

  convert_w<<<1216, 256, 0, stream>>>(Wq, Wk, Wv, wqh, wql, wkh, wkl, wvh, wvl);
  proj_mfma<416, 0><<<36, 256, 0, stream>>>(Q, wqh, wql, qhi, qlo);
  proj_mfma<416, 1><<<720, 256, 0, stream>>>(dbk, wkh, wkl, kvswz, nullptr);
  proj_mfma<384, 2><<<720, 256, 0, stream>>>(dbv, wvh, wvl, kvswz, nullptr);
  attn_kernel<<<2880, 512, 0, stream>>>(qhi, qlo, kvswz, rpartT, invl);
  weight_kernel<<<dim3(8, 4), 256, 0, stream>>>(invl, p, wbuf);
  reduce_out_k<<<2304, 256, 0, stream>>>(rpartT, wbuf, out);
}